// Round 4
// baseline (2467.684 us; speedup 1.0000x reference)
//
#include <hip/hip_runtime.h>
#include <hip/hip_bf16.h>
#include <math.h>

typedef __hip_bfloat16 bf16;

#define B_ 8
#define T_ 2048
#define D_ 512
#define H_ 2048
// T_*D_ = 2^20 per batch; T_*2*D_ = 2^21

__device__ __forceinline__ float b2f(unsigned short u) {
    return __uint_as_float((unsigned)u << 16);
}
__device__ __forceinline__ float ldb(const bf16* p, long i) {
    return b2f(((const unsigned short*)p)[i]);
}
// dual-dtype scalar load: flag!=0 -> f32, else bf16
__device__ __forceinline__ float dldf(const void* p, long i, int f32) {
    if (f32) return ((const float*)p)[i];
    return b2f(((const unsigned short*)p)[i]);
}
// dual-dtype 4-element contiguous load (index must be 4-aligned)
__device__ __forceinline__ void dld4(const void* p, long i, int f32, float o[4]) {
    if (f32) {
        float4 v = *reinterpret_cast<const float4*>((const float*)p + i);
        o[0] = v.x; o[1] = v.y; o[2] = v.z; o[3] = v.w;
    } else {
        ushort4 u = *reinterpret_cast<const ushort4*>((const unsigned short*)p + i);
        o[0] = b2f(u.x); o[1] = b2f(u.y); o[2] = b2f(u.z); o[3] = b2f(u.w);
    }
}

// -------- dtype sniffer: ln1_g is exactly ones. f32 ones -> first u32 = 0x3F800000;
// packed bf16 ones -> 0x3F803F80. flags[0]=input-is-f32, flags[1]=0 (ws bf16). --------
__global__ void sniff_kernel(const unsigned int* __restrict__ g, int* __restrict__ flags) {
    if (threadIdx.x == 0) {
        flags[0] = (g[0] == 0x3F800000u) ? 1 : 0;
        flags[1] = 0;
    }
}

// ---------------- LayerNorm over D=512, one block (256 thr) per row ----------------
__global__ __launch_bounds__(256) void ln_kernel(const void* __restrict__ x, const int* __restrict__ fX,
                                                 const void* __restrict__ g, const void* __restrict__ bb,
                                                 const int* __restrict__ fGB,
                                                 bf16* __restrict__ y) {
    int fx = *fX, fgb = *fGB;
    long base = (long)blockIdx.x * D_;
    int tid = threadIdx.x;
    float v0 = dldf(x, base + tid, fx);
    float v1 = dldf(x, base + tid + 256, fx);
    float s = v0 + v1;
#pragma unroll
    for (int off = 32; off > 0; off >>= 1) s += __shfl_down(s, off);
    __shared__ float red[4];
    int lane = tid & 63, wid = tid >> 6;
    if (lane == 0) red[wid] = s;
    __syncthreads();
    float mean = (red[0] + red[1] + red[2] + red[3]) * (1.0f / 512.0f);
    __syncthreads();
    float d0 = v0 - mean, d1 = v1 - mean;
    float vs = d0 * d0 + d1 * d1;
#pragma unroll
    for (int off = 32; off > 0; off >>= 1) vs += __shfl_down(vs, off);
    if (lane == 0) red[wid] = vs;
    __syncthreads();
    float var = (red[0] + red[1] + red[2] + red[3]) * (1.0f / 512.0f);
    float rstd = rsqrtf(var + 1e-5f);
    y[base + tid]       = __float2bfloat16(d0 * rstd * dldf(g, tid, fgb)       + dldf(bb, tid, fgb));
    y[base + tid + 256] = __float2bfloat16(d1 * rstd * dldf(g, tid + 256, fgb) + dldf(bb, tid + 256, fgb));
}

// ---------------- exp(w - rowmax(w)) : one block per row of [T,T] ----------------
__global__ __launch_bounds__(256) void expw_kernel(const void* __restrict__ w, const int* __restrict__ fW,
                                                   bf16* __restrict__ ew) {
    int fw = *fW;
    long base = (long)blockIdx.x * T_;
    int tid = threadIdx.x;
    float v[8];
    float mx = -3.4e38f;
#pragma unroll
    for (int i = 0; i < 8; ++i) {
        v[i] = dldf(w, base + tid + i * 256, fw);
        mx = fmaxf(mx, v[i]);
    }
#pragma unroll
    for (int off = 32; off > 0; off >>= 1) mx = fmaxf(mx, __shfl_down(mx, off));
    __shared__ float red[4];
    if ((tid & 63) == 0) red[tid >> 6] = mx;
    __syncthreads();
    float rmax = fmaxf(fmaxf(red[0], red[1]), fmaxf(red[2], red[3]));
#pragma unroll
    for (int i = 0; i < 8; ++i)
        ew[base + tid + i * 256] = __float2bfloat16(expf(v[i] - rmax));
}

// ---------------- max over batch dim of K [B,T,D] -> [T*D] (f32) ----------------
__global__ __launch_bounds__(256) void maxk_kernel(const bf16* __restrict__ K,
                                                   float* __restrict__ mk) {
    long i = (long)blockIdx.x * 256 + threadIdx.x;  // over T*D = 2^20
    float m = ldb(K, i);
#pragma unroll
    for (int b = 1; b < B_; ++b) m = fmaxf(m, ldb(K, (long)b * (T_ * D_) + i));
    mk[i] = m;
}

// ---------------- build KV2[b,t, 0:512]=expK*V, [512:1024]=expK ----------------
__global__ __launch_bounds__(256) void kv2_kernel(const bf16* __restrict__ K,
                                                  const bf16* __restrict__ V,
                                                  const float* __restrict__ mk,
                                                  bf16* __restrict__ kv2) {
    long i = (long)blockIdx.x * 256 + threadIdx.x;  // over B*T*D
    long td = i & (long)(T_ * D_ - 1);
    long b = i >> 20;
    long t = td >> 9;
    long d = td & (D_ - 1);
    float e = expf(ldb(K, i) - mk[td]);
    long base = (b << 21) + (t << 10);
    kv2[base + d]      = __float2bfloat16(e * ldb(V, i));
    kv2[base + D_ + d] = __float2bfloat16(e);
}

// ---------------- Yt = sigQ * num/den, in place on sigQ ----------------
__global__ __launch_bounds__(256) void yt_kernel(const bf16* __restrict__ nd,
                                                 bf16* __restrict__ q) {
    long i = (long)blockIdx.x * 256 + threadIdx.x;  // over B*T*D
    long td = i & (long)(T_ * D_ - 1);
    long b = i >> 20;
    long t = td >> 9;
    long d = td & (D_ - 1);
    long base = (b << 21) + (t << 10);
    float num = ldb(nd, base + d), den = ldb(nd, base + D_ + d);
    q[i] = __float2bfloat16(ldb(q, i) * num / den);
}

// ---------------- tiled GEMM: C = epi(A@B + bias) [+res], f32 accum ----------------
// A: bf16 [M,K] (workspace, shared across z); B: dual [K,N] (+z*bsB);
// bias: dual [N]; res: dual [M,N]; output: Cb (bf16) or Cf (f32), exactly one non-null.
// mode 0=none 1=sigmoid 2=gelu(exact).
__global__ __launch_bounds__(256) void gemm_kernel(
    const bf16* __restrict__ A,
    const void* __restrict__ Bm, const int* __restrict__ fB,
    const void* __restrict__ bias, const int* __restrict__ fBias,
    bf16* __restrict__ Cb, float* __restrict__ Cf,
    const void* __restrict__ res, const int* __restrict__ fRes,
    int M, int N, int K, int mode, long bsB, long bsC) {
    int fb = *fB;
    int fbias = bias ? *fBias : 0;
    int fres = res ? *fRes : 0;
    __shared__ float As[16][64];
    __shared__ float Bs[16][64];
    int tid = threadIdx.x;
    int tx = tid & 15, ty = tid >> 4;
    int m0 = blockIdx.y * 64, n0 = blockIdx.x * 64;
    float acc[4][4] = {};
    int arow = tid >> 2, acol = (tid & 3) * 4;   // A tile: 64 rows x 16 k
    int brow = tid >> 4, bcol = (tid & 15) * 4;  // B tile: 16 k x 64 cols
    long bbase = (long)blockIdx.z * bsB;

    for (int k0 = 0; k0 < K; k0 += 16) {
        float a4[4];
        ushort4 ua = *reinterpret_cast<const ushort4*>(
            (const unsigned short*)A + (long)(m0 + arow) * K + k0 + acol);
        a4[0] = b2f(ua.x); a4[1] = b2f(ua.y); a4[2] = b2f(ua.z); a4[3] = b2f(ua.w);
        As[acol + 0][arow] = a4[0];
        As[acol + 1][arow] = a4[1];
        As[acol + 2][arow] = a4[2];
        As[acol + 3][arow] = a4[3];
        float b4[4];
        dld4(Bm, bbase + (long)(k0 + brow) * N + n0 + bcol, fb, b4);
        Bs[brow][bcol + 0] = b4[0];
        Bs[brow][bcol + 1] = b4[1];
        Bs[brow][bcol + 2] = b4[2];
        Bs[brow][bcol + 3] = b4[3];
        __syncthreads();
#pragma unroll
        for (int kk = 0; kk < 16; ++kk) {
            float a_[4], b_[4];
#pragma unroll
            for (int i = 0; i < 4; ++i) a_[i] = As[kk][ty * 4 + i];
#pragma unroll
            for (int j = 0; j < 4; ++j) b_[j] = Bs[kk][tx * 4 + j];
#pragma unroll
            for (int i = 0; i < 4; ++i)
#pragma unroll
                for (int j = 0; j < 4; ++j) acc[i][j] = fmaf(a_[i], b_[j], acc[i][j]);
        }
        __syncthreads();
    }

    long cbase = (long)blockIdx.z * bsC;
#pragma unroll
    for (int i = 0; i < 4; ++i) {
        int row = m0 + ty * 4 + i;
#pragma unroll
        for (int j = 0; j < 4; ++j) {
            int col = n0 + tx * 4 + j;
            float v = acc[i][j];
            if (bias) v += dldf(bias, col, fbias);
            if (mode == 1) v = 1.0f / (1.0f + expf(-v));
            else if (mode == 2) v = 0.5f * v * (1.0f + erff(v * 0.70710678118654752f));
            long idx = cbase + (long)row * N + col;
            if (res) v += dldf(res, idx, fres);
            if (Cf) Cf[idx] = v;
            else Cb[idx] = __float2bfloat16(v);
        }
    }
}

extern "C" void kernel_launch(void* const* d_in, const int* in_sizes, int n_in,
                              void* d_out, int out_size, void* d_ws, size_t ws_size,
                              hipStream_t stream) {
    const void* x    = d_in[0];
    const void* ln1g = d_in[1];
    const void* ln1b = d_in[2];
    const void* Wk   = d_in[3];
    const void* bk   = d_in[4];
    const void* Wv   = d_in[5];
    const void* bv   = d_in[6];
    const void* Wq   = d_in[7];
    const void* bq   = d_in[8];
    const void* w    = d_in[9];
    const void* Wo   = d_in[10];
    const void* bo   = d_in[11];
    const void* ln2g = d_in[12];
    const void* ln2b = d_in[13];
    const void* W1   = d_in[14];
    const void* b1   = d_in[15];
    const void* W2   = d_in[16];
    const void* b2   = d_in[17];
    float* out = (float*)d_out;  // reference output dtype is float32

    const long S_BTD = (long)B_ * T_ * D_;      // 8,388,608
    const long S_TD  = (long)T_ * D_;           // 1,048,576
    const long S_TT  = (long)T_ * T_;           // 4,194,304
    const long S_B2D = (long)B_ * T_ * 2 * D_;  // 16,777,216

    // Workspace (bf16 elements unless noted), ~130 MB total (known to fit):
    bf16* h1     = (bf16*)d_ws;          // later h2
    bf16* Qb     = h1 + S_BTD;
    bf16* outres = Qb + S_BTD;
    bf16* ew     = outres + S_BTD;
    bf16* R1     = ew + S_TT;            // kv2; later hH spans R1+R2
    bf16* R2     = R1 + S_B2D;           // K | V; later nd
    float* mk    = (float*)(R2 + S_B2D); // S_TD f32
    int* flags   = (int*)(mk + S_TD);    // [0]=input f32?, [1]=0 (ws bf16)
    bf16* Kb  = R2;
    bf16* Vb  = R2 + S_BTD;
    bf16* kv2 = R1;
    bf16* nd  = R2;
    bf16* hH  = R1;   // B*T*H = 33,554,432 = 2*S_B2D elements, spans R1+R2 exactly
    bf16* h2  = h1;

    const int* fin = flags;      // input dtype flag
    const int* fws = flags + 1;  // constant 0 -> bf16

    const int M = B_ * T_;  // 16384

    // 0. sniff input dtype from ln1_g (exact ones)
    sniff_kernel<<<1, 64, 0, stream>>>((const unsigned int*)ln1g, flags);
    // 1. h1 = LN1(x)
    ln_kernel<<<M, 256, 0, stream>>>(x, fin, ln1g, ln1b, fin, h1);
    // 2-4. K, V, sigmoid(Q)
    dim3 gqkv(D_ / 64, M / 64, 1);
    gemm_kernel<<<gqkv, 256, 0, stream>>>(h1, Wk, fin, bk, fin, Kb, nullptr, nullptr, fws, M, D_, D_, 0, 0, 0);
    gemm_kernel<<<gqkv, 256, 0, stream>>>(h1, Wv, fin, bv, fin, Vb, nullptr, nullptr, fws, M, D_, D_, 0, 0, 0);
    gemm_kernel<<<gqkv, 256, 0, stream>>>(h1, Wq, fin, bq, fin, Qb, nullptr, nullptr, fws, M, D_, D_, 1, 0, 0);
    // 5. maxK over batch; 6. KV2 = [expK*V | expK]
    maxk_kernel<<<S_TD / 256, 256, 0, stream>>>(Kb, mk);
    kv2_kernel<<<S_BTD / 256, 256, 0, stream>>>(Kb, Vb, mk, kv2);
    // 7. exp_w
    expw_kernel<<<T_, 256, 0, stream>>>(w, fin, ew);
    // 8. ND[b] = exp_w @ KV2[b]  (M=2048, N=1024, K=2048, z=8) -> nd (overwrites K,V)
    dim3 gaft((2 * D_) / 64, T_ / 64, B_);
    gemm_kernel<<<gaft, 256, 0, stream>>>(ew, kv2, fws, nullptr, fws, nd, nullptr, nullptr, fws,
                                          T_, 2 * D_, T_, 0, (long)T_ * 2 * D_, (long)T_ * 2 * D_);
    // 9. Yt = sigQ * num/den (in place on Qb)
    yt_kernel<<<S_BTD / 256, 256, 0, stream>>>(nd, Qb);
    // 10. out = Yt@Wo + bo + x
    gemm_kernel<<<gqkv, 256, 0, stream>>>(Qb, Wo, fin, bo, fin, outres, nullptr, x, fin, M, D_, D_, 0, 0, 0);
    // 11. h2 = LN2(out)
    ln_kernel<<<M, 256, 0, stream>>>(outres, fws, ln2g, ln2b, fin, h2);
    // 12. hH = gelu(h2@W1 + b1)   (overwrites kv2+nd region)
    dim3 gff1(H_ / 64, M / 64, 1);
    gemm_kernel<<<gff1, 256, 0, stream>>>(h2, W1, fin, b1, fin, hH, nullptr, nullptr, fws, M, H_, D_, 2, 0, 0);
    // 13. y = gelu(hH@W2 + b2) + out -> f32 d_out
    dim3 gff2(D_ / 64, M / 64, 1);
    gemm_kernel<<<gff2, 256, 0, stream>>>(hH, W2, fin, b2, fin, nullptr, out, outres, fws, M, D_, H_, 2, 0, 0);
}

// Round 5
// 636.315 us; speedup vs baseline: 3.8781x; 3.8781x over previous
//
#include <hip/hip_runtime.h>
#include <hip/hip_bf16.h>
#include <math.h>

typedef __hip_bfloat16 bf16;
typedef __bf16 bf16x8 __attribute__((ext_vector_type(8)));
typedef float f32x4 __attribute__((ext_vector_type(4)));

#define B_ 8
#define T_ 2048
#define D_ 512
#define H_ 2048

__device__ __forceinline__ float b2f(unsigned short u) {
    return __uint_as_float((unsigned)u << 16);
}
__device__ __forceinline__ float ldf(const float* p, long i) { return p[i]; }
__device__ __forceinline__ float ldf(const bf16* p, long i) {
    return b2f(((const unsigned short*)p)[i]);
}

#define GLD16(g, l)                                                          \
    __builtin_amdgcn_global_load_lds(                                        \
        (const __attribute__((address_space(1))) void*)(g),                  \
        (__attribute__((address_space(3))) void*)(l), 16, 0, 0)

// ---------------- LayerNorm over D=512, one block (256 thr) per row ----------------
template <typename Tin>
__global__ __launch_bounds__(256) void ln_kernel(const Tin* __restrict__ x,
                                                 const float* __restrict__ g,
                                                 const float* __restrict__ bb,
                                                 bf16* __restrict__ y) {
    long base = (long)blockIdx.x * D_;
    int tid = threadIdx.x;
    float v0 = ldf(x, base + tid);
    float v1 = ldf(x, base + tid + 256);
    float s = v0 + v1;
#pragma unroll
    for (int off = 32; off > 0; off >>= 1) s += __shfl_down(s, off);
    __shared__ float red[4];
    int lane = tid & 63, wid = tid >> 6;
    if (lane == 0) red[wid] = s;
    __syncthreads();
    float mean = (red[0] + red[1] + red[2] + red[3]) * (1.0f / 512.0f);
    __syncthreads();
    float d0 = v0 - mean, d1 = v1 - mean;
    float vs = d0 * d0 + d1 * d1;
#pragma unroll
    for (int off = 32; off > 0; off >>= 1) vs += __shfl_down(vs, off);
    if (lane == 0) red[wid] = vs;
    __syncthreads();
    float var = (red[0] + red[1] + red[2] + red[3]) * (1.0f / 512.0f);
    float rstd = rsqrtf(var + 1e-5f);
    y[base + tid]       = __float2bfloat16(d0 * rstd * g[tid]       + bb[tid]);
    y[base + tid + 256] = __float2bfloat16(d1 * rstd * g[tid + 256] + bb[tid + 256]);
}

// ---------------- exp(w - rowmax(w)) : one block per row of [T,T] ----------------
__global__ __launch_bounds__(256) void expw_kernel(const float* __restrict__ w,
                                                   bf16* __restrict__ ew) {
    long base = (long)blockIdx.x * T_;
    int tid = threadIdx.x;
    float v[8];
    float mx = -3.4e38f;
#pragma unroll
    for (int i = 0; i < 8; ++i) {
        v[i] = w[base + tid + i * 256];
        mx = fmaxf(mx, v[i]);
    }
#pragma unroll
    for (int off = 32; off > 0; off >>= 1) mx = fmaxf(mx, __shfl_down(mx, off));
    __shared__ float red[4];
    if ((tid & 63) == 0) red[tid >> 6] = mx;
    __syncthreads();
    float rmax = fmaxf(fmaxf(red[0], red[1]), fmaxf(red[2], red[3]));
#pragma unroll
    for (int i = 0; i < 8; ++i)
        ew[base + tid + i * 256] = __float2bfloat16(expf(v[i] - rmax));
}

// ---------------- max over batch dim of K [B,T,D] -> [T*D] (f32) ----------------
__global__ __launch_bounds__(256) void maxk_kernel(const bf16* __restrict__ K,
                                                   float* __restrict__ mk) {
    long i = (long)blockIdx.x * 256 + threadIdx.x;
    float m = ldf(K, i);
#pragma unroll
    for (int b = 1; b < B_; ++b) m = fmaxf(m, ldf(K, (long)b * (T_ * D_) + i));
    mk[i] = m;
}

// ------- build kv2T[b][n][t], n<512: expK*V (d=n); n>=512: expK (d=n-512) -------
// grid (T/64, D/64, B), block 256. LDS-transposed for coalesced in+out.
__global__ __launch_bounds__(256) void kv2t_kernel(const bf16* __restrict__ K_,
                                                   const bf16* __restrict__ V_,
                                                   const float* __restrict__ mk,
                                                   bf16* __restrict__ kv2t) {
    __shared__ float sev[64][65];
    __shared__ float se[64][65];
    int tx = threadIdx.x & 63, ty = threadIdx.x >> 6;
    int t0 = blockIdx.x * 64, d0 = blockIdx.y * 64, b = blockIdx.z;
    long ibase = (long)b << 20;
#pragma unroll
    for (int r = 0; r < 16; ++r) {
        int tl = r * 4 + ty;
        long mi = (long)(t0 + tl) * D_ + d0 + tx;
        float e = expf(ldf(K_, ibase + mi) - mk[mi]);
        sev[tl][tx] = e * ldf(V_, ibase + mi);
        se[tl][tx] = e;
    }
    __syncthreads();
    long obase = (long)b << 21;
#pragma unroll
    for (int r = 0; r < 16; ++r) {
        int dl = r * 4 + ty;
        kv2t[obase + (long)(d0 + dl) * T_ + t0 + tx]        = __float2bfloat16(sev[tx][dl]);
        kv2t[obase + (long)(512 + d0 + dl) * T_ + t0 + tx]  = __float2bfloat16(se[tx][dl]);
    }
}

// ---------------- Yt = sigQ * num/den, in place on sigQ ----------------
__global__ __launch_bounds__(256) void yt_kernel(const bf16* __restrict__ nd,
                                                 bf16* __restrict__ q) {
    long i = (long)blockIdx.x * 256 + threadIdx.x;
    long td = i & (long)(T_ * D_ - 1);
    long b = i >> 20;
    long t = td >> 9;
    long d = td & (D_ - 1);
    long base = (b << 21) + (t << 10);
    float num = ldf(nd, base + d), den = ldf(nd, base + D_ + d);
    q[i] = __float2bfloat16(ldf(q, i) * num / den);
}

// ---------------- weight transpose + f32->bf16: W[K,N] -> WT[N,K] ----------------
__global__ __launch_bounds__(256) void wtrans_kernel(const float* __restrict__ W,
                                                     bf16* __restrict__ WT,
                                                     int K, int N) {
    __shared__ float s[64][65];
    int tx = threadIdx.x & 63, ty = threadIdx.x >> 6;
    int n0 = blockIdx.x * 64, k0 = blockIdx.y * 64;
#pragma unroll
    for (int r = 0; r < 16; ++r) {
        int kl = r * 4 + ty;
        s[kl][tx] = W[(long)(k0 + kl) * N + n0 + tx];
    }
    __syncthreads();
#pragma unroll
    for (int r = 0; r < 16; ++r) {
        int nl = r * 4 + ty;
        WT[(long)(n0 + nl) * K + k0 + tx] = __float2bfloat16(s[tx][nl]);
    }
}

// ---------------- MFMA GEMM (m97 structure): C = epi(A@Bt^T + bias) [+res] --------
// A: bf16 [M,K] row-major (shared over z). Bt: bf16 [N,K] row-major (+z*bsB).
// 128x128 tile, 4 waves in 2x2, each 64x64 via 4x4 MFMA 16x16x32, BK=32.
// mode 0=none 1=sigmoid 2=gelu(exact). Output Cb bf16 or Cf f32.
__global__ __launch_bounds__(256) void mfma_gemm(
    const bf16* __restrict__ A, const bf16* __restrict__ Bt,
    const float* __restrict__ bias,
    bf16* __restrict__ Cb, float* __restrict__ Cf,
    const bf16* __restrict__ resb, const float* __restrict__ resf,
    int M, int N, int K, int mode, long bsB, long bsC) {
    __shared__ short As[128 * 32];
    __shared__ short Bs[128 * 32];
    int tid = threadIdx.x;
    int lane = tid & 63, wave = tid >> 6;
    int wm = wave >> 1, wn = wave & 1;
    int m0 = blockIdx.y * 128, n0 = blockIdx.x * 128;
    const short* Ag = (const short*)A;
    const short* Bg = (const short*)Bt + (long)blockIdx.z * bsB;

    // staging: wave handles 32 rows of A-tile and 32 rows of Bt-tile (2 issues each)
    int lr = lane >> 2;          // 0..15 row within issue
    int le = (lane & 3) * 8;     // element offset within 32-elem row (16B chunks)
    const short* ga0 = Ag + (long)(m0 + wave * 32 + lr) * K + le;
    const short* ga1 = ga0 + 16L * K;
    const short* gb0 = Bg + (long)(n0 + wave * 32 + lr) * K + le;
    const short* gb1 = gb0 + 16L * K;
    short* la = As + wave * 32 * 32;
    short* lb = Bs + wave * 32 * 32;

    f32x4 acc[4][4];
    f32x4 zz = {0.f, 0.f, 0.f, 0.f};
#pragma unroll
    for (int i = 0; i < 4; ++i)
#pragma unroll
        for (int j = 0; j < 4; ++j) acc[i][j] = zz;

    int fr = lane & 15;          // fragment row (A-m / B-n)
    int fk = (lane >> 4) * 8;    // fragment k offset

    for (int k0 = 0; k0 < K; k0 += 32) {
        GLD16(ga0 + k0, la);
        GLD16(ga1 + k0, la + 16 * 32);
        GLD16(gb0 + k0, lb);
        GLD16(gb1 + k0, lb + 16 * 32);
        __syncthreads();
        bf16x8 af[4], bv[4];
#pragma unroll
        for (int mi = 0; mi < 4; ++mi)
            af[mi] = *(const bf16x8*)(As + (wm * 64 + mi * 16 + fr) * 32 + fk);
#pragma unroll
        for (int ni = 0; ni < 4; ++ni)
            bv[ni] = *(const bf16x8*)(Bs + (wn * 64 + ni * 16 + fr) * 32 + fk);
#pragma unroll
        for (int mi = 0; mi < 4; ++mi)
#pragma unroll
            for (int ni = 0; ni < 4; ++ni)
                acc[mi][ni] = __builtin_amdgcn_mfma_f32_16x16x32_bf16(
                    af[mi], bv[ni], acc[mi][ni], 0, 0, 0);
        __syncthreads();
    }

    // epilogue: C/D layout col=lane&15, row=(lane>>4)*4+reg (m89-verified)
    int cc = lane & 15, cr = (lane >> 4) * 4;
    long cbase = (long)blockIdx.z * bsC;
#pragma unroll
    for (int mi = 0; mi < 4; ++mi) {
#pragma unroll
        for (int ni = 0; ni < 4; ++ni) {
            int row0 = m0 + wm * 64 + mi * 16 + cr;
            int col = n0 + wn * 64 + ni * 16 + cc;
            float bvl = bias ? bias[col] : 0.0f;
#pragma unroll
            for (int r = 0; r < 4; ++r) {
                float v = acc[mi][ni][r] + bvl;
                if (mode == 1) v = 1.0f / (1.0f + expf(-v));
                else if (mode == 2) v = 0.5f * v * (1.0f + erff(v * 0.70710678118654752f));
                long idx = cbase + (long)(row0 + r) * N + col;
                if (resf) v += resf[idx];
                if (resb) v += ldf(resb, idx);
                if (Cf) Cf[idx] = v;
                else Cb[idx] = __float2bfloat16(v);
            }
        }
    }
}

extern "C" void kernel_launch(void* const* d_in, const int* in_sizes, int n_in,
                              void* d_out, int out_size, void* d_ws, size_t ws_size,
                              hipStream_t stream) {
    const float* x    = (const float*)d_in[0];
    const float* ln1g = (const float*)d_in[1];
    const float* ln1b = (const float*)d_in[2];
    const float* Wk   = (const float*)d_in[3];
    const float* bk   = (const float*)d_in[4];
    const float* Wv   = (const float*)d_in[5];
    const float* bv   = (const float*)d_in[6];
    const float* Wq   = (const float*)d_in[7];
    const float* bq   = (const float*)d_in[8];
    const float* w    = (const float*)d_in[9];
    const float* Wo   = (const float*)d_in[10];
    const float* bo   = (const float*)d_in[11];
    const float* ln2g = (const float*)d_in[12];
    const float* ln2b = (const float*)d_in[13];
    const float* W1   = (const float*)d_in[14];
    const float* b1   = (const float*)d_in[15];
    const float* W2   = (const float*)d_in[16];
    const float* b2   = (const float*)d_in[17];
    float* out = (float*)d_out;

    const long S_BTD = (long)B_ * T_ * D_;      // 8,388,608
    const long S_TD  = (long)T_ * D_;           // 1,048,576
    const long S_TT  = (long)T_ * T_;           // 4,194,304
    const long S_B2D = (long)B_ * T_ * 2 * D_;  // 16,777,216
    const long S_DD  = (long)D_ * D_;           // 262,144

    // Workspace (bf16 elems unless noted) ~137 MB:
    bf16* h1     = (bf16*)d_ws;          // later h2
    bf16* Qb     = h1 + S_BTD;
    bf16* outres = Qb + S_BTD;
    bf16* ew     = outres + S_BTD;
    bf16* R1     = ew + S_TT;            // kv2t; later hH low half
    bf16* R2     = R1 + S_B2D;           // K|V; later nd; hH high half
    float* mk    = (float*)(R2 + S_B2D); // S_TD f32
    bf16* WkT    = (bf16*)(mk + S_TD);
    bf16* WvT    = WkT + S_DD;
    bf16* WqT    = WvT + S_DD;
    bf16* WoT    = WqT + S_DD;
    bf16* W1T    = WoT + S_DD;           // [H,D] = 2048x512
    bf16* W2T    = W1T + (long)D_ * H_;  // [D,H] = 512x2048
    bf16* Kb  = R2;
    bf16* Vb  = R2 + S_BTD;
    bf16* kv2t = R1;
    bf16* nd  = R2;
    bf16* hH  = R1;   // spans R1+R2 (B*T*H = 2*S_B2D)
    bf16* h2  = h1;

    const int M = B_ * T_;  // 16384

    // 0. weight transposes (f32 -> bf16, [K,N] -> [N,K])
    wtrans_kernel<<<dim3(8, 8), 256, 0, stream>>>(Wk, WkT, D_, D_);
    wtrans_kernel<<<dim3(8, 8), 256, 0, stream>>>(Wv, WvT, D_, D_);
    wtrans_kernel<<<dim3(8, 8), 256, 0, stream>>>(Wq, WqT, D_, D_);
    wtrans_kernel<<<dim3(8, 8), 256, 0, stream>>>(Wo, WoT, D_, D_);
    wtrans_kernel<<<dim3(32, 8), 256, 0, stream>>>(W1, W1T, D_, H_);
    wtrans_kernel<<<dim3(8, 32), 256, 0, stream>>>(W2, W2T, H_, D_);
    // 1. h1 = LN1(x)
    ln_kernel<float><<<M, 256, 0, stream>>>(x, ln1g, ln1b, h1);
    // 2-4. K, V, sigmoid(Q)
    dim3 gqkv(D_ / 128, M / 128, 1);
    mfma_gemm<<<gqkv, 256, 0, stream>>>(h1, WkT, bk, Kb, nullptr, nullptr, nullptr, M, D_, D_, 0, 0, 0);
    mfma_gemm<<<gqkv, 256, 0, stream>>>(h1, WvT, bv, Vb, nullptr, nullptr, nullptr, M, D_, D_, 0, 0, 0);
    mfma_gemm<<<gqkv, 256, 0, stream>>>(h1, WqT, bq, Qb, nullptr, nullptr, nullptr, M, D_, D_, 1, 0, 0);
    // 5. mk = max_b K; 6. kv2t = [expK*V | expK]^T per batch
    maxk_kernel<<<S_TD / 256, 256, 0, stream>>>(Kb, mk);
    kv2t_kernel<<<dim3(T_ / 64, D_ / 64, B_), 256, 0, stream>>>(Kb, Vb, mk, kv2t);
    // 7. exp_w
    expw_kernel<<<T_, 256, 0, stream>>>(w, ew);
    // 8. nd[b] = ew @ kv2t[b]^T  (M=2048, N=1024, K=2048)
    dim3 gaft(1024 / 128, T_ / 128, B_);
    mfma_gemm<<<gaft, 256, 0, stream>>>(ew, kv2t, nullptr, nd, nullptr, nullptr, nullptr,
                                        T_, 1024, T_, 0, (long)1024 * T_, (long)T_ * 1024);
    // 9. Yt = sigQ * num/den (in place on Qb)
    yt_kernel<<<S_BTD / 256, 256, 0, stream>>>(nd, Qb);
    // 10. out = Yt@Wo + bo + x
    mfma_gemm<<<gqkv, 256, 0, stream>>>(Qb, WoT, bo, outres, nullptr, nullptr, x, M, D_, D_, 0, 0, 0);
    // 11. h2 = LN2(out)
    ln_kernel<bf16><<<M, 256, 0, stream>>>(outres, ln2g, ln2b, h2);
    // 12. hH = gelu(h2@W1 + b1)
    dim3 gff1(H_ / 128, M / 128, 1);
    mfma_gemm<<<gff1, 256, 0, stream>>>(h2, W1T, b1, hH, nullptr, nullptr, nullptr, M, H_, D_, 2, 0, 0);
    // 13. y = gelu(hH@W2 + b2) + out -> f32 d_out
    dim3 gff2(D_ / 128, M / 128, 1);
    mfma_gemm<<<gff2, 256, 0, stream>>>(hH, W2T, b2, nullptr, out, outres, nullptr, M, D_, H_, 2, 0, 0);
}